// Round 5
// baseline (37.512 us; speedup 1.0000x reference)
//
#include <hip/hip_runtime.h>
#include <math.h>

#define NB 32   // batch
#define CB 32   // capsule channels C
#define KC 10   // classes
#define PAD_LRT 260  // floats per lrT row
#define PAD_TP  168  // floats per Tp row

// s_part layout: s[n][d=160][c=32]  (c minor -> contiguous reduction reads)

// sum over c of s[n][tid][0..31], then squash scale for this (k,d); tid<160
__device__ __forceinline__ float squash_term(const float* __restrict__ sp, int n, int tid) {
    const float4* p = (const float4*)(sp + ((size_t)n * 160 + tid) * 32);
    float4 q0 = p[0], q1 = p[1], q2 = p[2], q3 = p[3];
    float4 q4 = p[4], q5 = p[5], q6 = p[6], q7 = p[7];
    float ssum = (((q0.x + q0.y) + (q0.z + q0.w)) + ((q1.x + q1.y) + (q1.z + q1.w)))
               + (((q2.x + q2.y) + (q2.z + q2.w)) + ((q3.x + q3.y) + (q3.z + q3.w)))
               + (((q4.x + q4.y) + (q4.z + q4.w)) + ((q5.x + q5.y) + (q5.z + q5.w)))
               + (((q6.x + q6.y) + (q6.z + q6.w)) + ((q7.x + q7.y) + (q7.z + q7.w)));
    float sq = ssum * ssum;
    sq += __shfl_xor(sq, 1, 16);
    sq += __shfl_xor(sq, 2, 16);
    sq += __shfl_xor(sq, 4, 16);
    sq += __shfl_xor(sq, 8, 16);
    sq = fmaxf(sq, 1e-30f);
    return ssum * sq / ((1.f + sq) * sqrtf(sq));
}

// b = lr.E, softmax over k, write c row-major [k][m=tid]
__device__ __forceinline__ void softmax_c(const float lr[16], const float* __restrict__ E,
                                          float* __restrict__ c_out, int tid) {
    float b[KC];
    #pragma unroll
    for (int k = 0; k < KC; ++k) {
        const float4* e4 = (const float4*)(E + k * 16);
        float4 e0 = e4[0], e1 = e4[1], e2 = e4[2], e3 = e4[3];
        float acc = 0.f;
        acc = fmaf(lr[0], e0.x, acc);  acc = fmaf(lr[1], e0.y, acc);
        acc = fmaf(lr[2], e0.z, acc);  acc = fmaf(lr[3], e0.w, acc);
        acc = fmaf(lr[4], e1.x, acc);  acc = fmaf(lr[5], e1.y, acc);
        acc = fmaf(lr[6], e1.z, acc);  acc = fmaf(lr[7], e1.w, acc);
        acc = fmaf(lr[8], e2.x, acc);  acc = fmaf(lr[9], e2.y, acc);
        acc = fmaf(lr[10], e2.z, acc); acc = fmaf(lr[11], e2.w, acc);
        acc = fmaf(lr[12], e3.x, acc); acc = fmaf(lr[13], e3.y, acc);
        acc = fmaf(lr[14], e3.z, acc); acc = fmaf(lr[15], e3.w, acc);
        b[k] = acc;
    }
    float mx = b[0];
    #pragma unroll
    for (int k = 1; k < KC; ++k) mx = fmaxf(mx, b[k]);
    float sum = 0.f;
    #pragma unroll
    for (int k = 0; k < KC; ++k) { b[k] = __expf(b[k] - mx); sum += b[k]; }
    const float inv = 1.f / sum;
    #pragma unroll
    for (int k = 0; k < KC; ++k) c_out[k * 256 + tid] = b[k] * inv;
}

// thread = (mg of 16 m, ij-pair, k-half): 28 b128 reads per thread (8 lrT + 20 c)
__device__ __forceinline__ void tp_stage(const float* __restrict__ lrTp,
                                         const float* __restrict__ cl,
                                         float* __restrict__ Tp, int tid) {
    const int mg  = tid >> 4;
    const int r   = tid & 15;
    const int ij0 = (r & 7) * 2;     // handles ij0, ij0+1
    const int k0  = (r >> 3) * 5;    // handles k0..k0+4
    const float4* lp0 = (const float4*)(lrTp + ij0 * PAD_LRT + mg * 16);
    const float4* lp1 = (const float4*)(lrTp + (ij0 + 1) * PAD_LRT + mg * 16);
    float4 a0 = lp0[0], a1 = lp0[1], a2 = lp0[2], a3 = lp0[3];
    float4 b0 = lp1[0], b1 = lp1[1], b2 = lp1[2], b3 = lp1[3];
    #pragma unroll
    for (int kk = 0; kk < 5; ++kk) {
        const int k = k0 + kk;
        const float4* cp = (const float4*)(cl + k * 256 + mg * 16);
        float4 c0 = cp[0], c1 = cp[1], c2 = cp[2], c3 = cp[3];
        float t0 = 0.f, t1 = 0.f;
        t0 = fmaf(c0.x, a0.x, t0); t1 = fmaf(c0.x, b0.x, t1);
        t0 = fmaf(c0.y, a0.y, t0); t1 = fmaf(c0.y, b0.y, t1);
        t0 = fmaf(c0.z, a0.z, t0); t1 = fmaf(c0.z, b0.z, t1);
        t0 = fmaf(c0.w, a0.w, t0); t1 = fmaf(c0.w, b0.w, t1);
        t0 = fmaf(c1.x, a1.x, t0); t1 = fmaf(c1.x, b1.x, t1);
        t0 = fmaf(c1.y, a1.y, t0); t1 = fmaf(c1.y, b1.y, t1);
        t0 = fmaf(c1.z, a1.z, t0); t1 = fmaf(c1.z, b1.z, t1);
        t0 = fmaf(c1.w, a1.w, t0); t1 = fmaf(c1.w, b1.w, t1);
        t0 = fmaf(c2.x, a2.x, t0); t1 = fmaf(c2.x, b2.x, t1);
        t0 = fmaf(c2.y, a2.y, t0); t1 = fmaf(c2.y, b2.y, t1);
        t0 = fmaf(c2.z, a2.z, t0); t1 = fmaf(c2.z, b2.z, t1);
        t0 = fmaf(c2.w, a2.w, t0); t1 = fmaf(c2.w, b2.w, t1);
        t0 = fmaf(c3.x, a3.x, t0); t1 = fmaf(c3.x, b3.x, t1);
        t0 = fmaf(c3.y, a3.y, t0); t1 = fmaf(c3.y, b3.y, t1);
        t0 = fmaf(c3.z, a3.z, t0); t1 = fmaf(c3.z, b3.z, t1);
        t0 = fmaf(c3.w, a3.w, t0); t1 = fmaf(c3.w, b3.w, t1);
        Tp[mg * PAD_TP + k * 16 + ij0]     = t0;
        Tp[mg * PAD_TP + k * 16 + ij0 + 1] = t1;
    }
}

__device__ __forceinline__ void t_reduce(const float* __restrict__ Tp,
                                         float* __restrict__ T, int tid) {
    if (tid < 160) {
        float t = 0.f;
        #pragma unroll
        for (int mg = 0; mg < 16; ++mg) t += Tp[mg * PAD_TP + tid];
        T[tid] = t;
    }
}

// s[n][d=tid][c] = sum_j T[k][i*4+j] * w[k][j*4+le]
__device__ __forceinline__ void s_write(const float* __restrict__ T,
                                        const float* __restrict__ w,
                                        float* __restrict__ s, int n, int c, int tid) {
    if (tid < 160) {
        const int k = tid >> 4;
        const int i = (tid >> 2) & 3;
        const int le = tid & 3;
        float sv = 0.f;
        #pragma unroll
        for (int j = 0; j < 4; ++j)
            sv = fmaf(T[k * 16 + i * 4 + j], w[k * 16 + j * 4 + le], sv);
        s[((size_t)n * 160 + tid) * 32 + c] = sv;
    }
}

__global__ __launch_bounds__(256) void caps_main(
    const float* __restrict__ l, const float* __restrict__ g,
    const float* __restrict__ weight,
    const float* __restrict__ sp0, const float* __restrict__ sp1,
    float* __restrict__ s_out, int nv)
{
    __shared__ __align__(16) float w_lds[160];
    __shared__ __align__(16) float aeff_lds[160];
    __shared__ __align__(16) float E_lds[160];
    __shared__ __align__(16) float lrT[16 * PAD_LRT];
    __shared__ __align__(16) float c_lds[KC * 256];
    __shared__ __align__(16) float Tp[16 * PAD_TP];
    __shared__ __align__(16) float T_lds[160];

    const int tid = threadIdx.x;
    const int n = blockIdx.x >> 5;
    const int c = blockIdx.x & 31;

    if (tid < 160) w_lds[tid] = weight[c * 160 + tid];

    // per-thread pose (coalesced 256B/wave-inst) + transposed LDS copy
    float lr[16];
    const float* lbase = l + (size_t)(n * CB + c) * 4096 + tid;
    #pragma unroll
    for (int ij = 0; ij < 16; ++ij) lr[ij] = lbase[ij * 256];
    #pragma unroll
    for (int ij = 0; ij < 16; ++ij) lrT[ij * PAD_LRT + tid] = lr[ij];

    if (tid < 160) {
        float a = g[n * 160 + tid];
        if (nv > 0) a += squash_term(sp0, n, tid);
        if (nv > 1) a += squash_term(sp1, n, tid);
        aeff_lds[tid] = a;
    }
    __syncthreads();

    if (tid < 160) {
        const int k = tid >> 4, i = (tid >> 2) & 3, j = tid & 3;
        const float* av = aeff_lds + k * 16;
        const float* wk = w_lds + k * 16;
        float e = 0.f;
        #pragma unroll
        for (int ll = 0; ll < 4; ++ll)
            e = fmaf(av[i * 4 + ll], wk[j * 4 + ll], e);
        E_lds[tid] = e;
    }
    __syncthreads();

    softmax_c(lr, E_lds, c_lds, tid);
    __syncthreads();
    tp_stage(lrT, c_lds, Tp, tid);
    __syncthreads();
    t_reduce(Tp, T_lds, tid);
    __syncthreads();
    s_write(T_lds, w_lds, s_out, n, c, tid);
}

// final: v = squash(sum_c s2), a = sigmoid(||v||); out = [a(320) | v(5120)]
__global__ __launch_bounds__(256) void caps_final(
    const float* __restrict__ sp2, float* __restrict__ out)
{
    const int idx = blockIdx.x * 256 + threadIdx.x;  // 0..5119
    const int nk = idx >> 4;
    const int d = idx & 15;
    const int n = nk / 10;
    const int k = nk - n * 10;
    const float4* p = (const float4*)(sp2 + ((size_t)n * 160 + k * 16 + d) * 32);
    float4 q0 = p[0], q1 = p[1], q2 = p[2], q3 = p[3];
    float4 q4 = p[4], q5 = p[5], q6 = p[6], q7 = p[7];
    float ssum = (((q0.x + q0.y) + (q0.z + q0.w)) + ((q1.x + q1.y) + (q1.z + q1.w)))
               + (((q2.x + q2.y) + (q2.z + q2.w)) + ((q3.x + q3.y) + (q3.z + q3.w)))
               + (((q4.x + q4.y) + (q4.z + q4.w)) + ((q5.x + q5.y) + (q5.z + q5.w)))
               + (((q6.x + q6.y) + (q6.z + q6.w)) + ((q7.x + q7.y) + (q7.z + q7.w)));
    float sq = ssum * ssum;
    sq += __shfl_xor(sq, 1, 16);
    sq += __shfl_xor(sq, 2, 16);
    sq += __shfl_xor(sq, 4, 16);
    sq += __shfl_xor(sq, 8, 16);
    sq = fmaxf(sq, 1e-30f);
    out[320 + nk * 16 + d] = ssum * sq / ((1.f + sq) * sqrtf(sq));
    if (d == 0) {
        const float nrm = sq / (1.f + sq);   // == ||v||
        out[nk] = 1.f / (1.f + __expf(-nrm));
    }
}

extern "C" void kernel_launch(void* const* d_in, const int* in_sizes, int n_in,
                              void* d_out, int out_size, void* d_ws, size_t ws_size,
                              hipStream_t stream) {
    const float* l = (const float*)d_in[0];
    const float* g = (const float*)d_in[1];
    const float* w = (const float*)d_in[2];
    float* out = (float*)d_out;
    float* ws = (float*)d_ws;

    float* s0 = ws;                 // (N,160,32) = 163840 floats each
    float* s1 = ws + 163840;
    float* s2 = ws + 327680;

    caps_main<<<dim3(NB * CB), dim3(256), 0, stream>>>(l, g, w, nullptr, nullptr, s0, 0);
    caps_main<<<dim3(NB * CB), dim3(256), 0, stream>>>(l, g, w, s0, nullptr, s1, 1);
    caps_main<<<dim3(NB * CB), dim3(256), 0, stream>>>(l, g, w, s0, s1, s2, 2);
    caps_final<<<dim3(20), dim3(256), 0, stream>>>(s2, out);
}

// Round 6
// 31.076 us; speedup vs baseline: 1.2071x; 1.2071x over previous
//
#include <hip/hip_runtime.h>
#include <math.h>

#define NB 32   // batch
#define CB 32   // capsule channels C
#define KC 10   // classes
#define PAD_LRT 260  // floats per lrT row
#define PAD_TP  168  // floats per Tp row

// s_part layout: s[n][c][160] (block-contiguous writes, lane-coalesced c-reduction reads)

// sum over c of s_part[n][c][tid] followed by squash scaling for this (k,d); tid<160
__device__ __forceinline__ float squash_term(const float* __restrict__ sp, int n, int tid) {
    const float* p = sp + (size_t)n * (CB * 160) + tid;
    float t0 = 0.f, t1 = 0.f, t2 = 0.f, t3 = 0.f;
    #pragma unroll
    for (int cc = 0; cc < 32; cc += 4) {
        t0 += p[cc * 160];       t1 += p[(cc + 1) * 160];
        t2 += p[(cc + 2) * 160]; t3 += p[(cc + 3) * 160];
    }
    float ssum = (t0 + t1) + (t2 + t3);
    float sq = ssum * ssum;
    sq += __shfl_xor(sq, 1, 16);
    sq += __shfl_xor(sq, 2, 16);
    sq += __shfl_xor(sq, 4, 16);
    sq += __shfl_xor(sq, 8, 16);
    sq = fmaxf(sq, 1e-30f);
    return ssum * sq / ((1.f + sq) * sqrtf(sq));
}

// b = lr.E, softmax over k, write c row-major [k][m=tid]
__device__ __forceinline__ void softmax_c(const float lr[16], const float* __restrict__ E,
                                          float* __restrict__ c_out, int tid) {
    float b[KC];
    #pragma unroll
    for (int k = 0; k < KC; ++k) {
        const float4* e4 = (const float4*)(E + k * 16);
        float4 e0 = e4[0], e1 = e4[1], e2 = e4[2], e3 = e4[3];
        float acc = 0.f;
        acc = fmaf(lr[0], e0.x, acc);  acc = fmaf(lr[1], e0.y, acc);
        acc = fmaf(lr[2], e0.z, acc);  acc = fmaf(lr[3], e0.w, acc);
        acc = fmaf(lr[4], e1.x, acc);  acc = fmaf(lr[5], e1.y, acc);
        acc = fmaf(lr[6], e1.z, acc);  acc = fmaf(lr[7], e1.w, acc);
        acc = fmaf(lr[8], e2.x, acc);  acc = fmaf(lr[9], e2.y, acc);
        acc = fmaf(lr[10], e2.z, acc); acc = fmaf(lr[11], e2.w, acc);
        acc = fmaf(lr[12], e3.x, acc); acc = fmaf(lr[13], e3.y, acc);
        acc = fmaf(lr[14], e3.z, acc); acc = fmaf(lr[15], e3.w, acc);
        b[k] = acc;
    }
    float mx = b[0];
    #pragma unroll
    for (int k = 1; k < KC; ++k) mx = fmaxf(mx, b[k]);
    float sum = 0.f;
    #pragma unroll
    for (int k = 0; k < KC; ++k) { b[k] = __expf(b[k] - mx); sum += b[k]; }
    const float inv = 1.f / sum;
    #pragma unroll
    for (int k = 0; k < KC; ++k) c_out[k * 256 + tid] = b[k] * inv;
}

// thread = (mg of 16 m, ij-pair, k-half): 28 b128 reads per thread (8 lrT + 20 c)
__device__ __forceinline__ void tp_stage(const float* __restrict__ lrTp,
                                         const float* __restrict__ cl,
                                         float* __restrict__ Tp, int tid) {
    const int mg  = tid >> 4;
    const int r   = tid & 15;
    const int ij0 = (r & 7) * 2;     // handles ij0, ij0+1
    const int k0  = (r >> 3) * 5;    // handles k0..k0+4
    const float4* lp0 = (const float4*)(lrTp + ij0 * PAD_LRT + mg * 16);
    const float4* lp1 = (const float4*)(lrTp + (ij0 + 1) * PAD_LRT + mg * 16);
    float4 a0 = lp0[0], a1 = lp0[1], a2 = lp0[2], a3 = lp0[3];
    float4 b0 = lp1[0], b1 = lp1[1], b2 = lp1[2], b3 = lp1[3];
    #pragma unroll
    for (int kk = 0; kk < 5; ++kk) {
        const int k = k0 + kk;
        const float4* cp = (const float4*)(cl + k * 256 + mg * 16);
        float4 c0 = cp[0], c1 = cp[1], c2 = cp[2], c3 = cp[3];
        float t0 = 0.f, t1 = 0.f;
        t0 = fmaf(c0.x, a0.x, t0); t1 = fmaf(c0.x, b0.x, t1);
        t0 = fmaf(c0.y, a0.y, t0); t1 = fmaf(c0.y, b0.y, t1);
        t0 = fmaf(c0.z, a0.z, t0); t1 = fmaf(c0.z, b0.z, t1);
        t0 = fmaf(c0.w, a0.w, t0); t1 = fmaf(c0.w, b0.w, t1);
        t0 = fmaf(c1.x, a1.x, t0); t1 = fmaf(c1.x, b1.x, t1);
        t0 = fmaf(c1.y, a1.y, t0); t1 = fmaf(c1.y, b1.y, t1);
        t0 = fmaf(c1.z, a1.z, t0); t1 = fmaf(c1.z, b1.z, t1);
        t0 = fmaf(c1.w, a1.w, t0); t1 = fmaf(c1.w, b1.w, t1);
        t0 = fmaf(c2.x, a2.x, t0); t1 = fmaf(c2.x, b2.x, t1);
        t0 = fmaf(c2.y, a2.y, t0); t1 = fmaf(c2.y, b2.y, t1);
        t0 = fmaf(c2.z, a2.z, t0); t1 = fmaf(c2.z, b2.z, t1);
        t0 = fmaf(c2.w, a2.w, t0); t1 = fmaf(c2.w, b2.w, t1);
        t0 = fmaf(c3.x, a3.x, t0); t1 = fmaf(c3.x, b3.x, t1);
        t0 = fmaf(c3.y, a3.y, t0); t1 = fmaf(c3.y, b3.y, t1);
        t0 = fmaf(c3.z, a3.z, t0); t1 = fmaf(c3.z, b3.z, t1);
        t0 = fmaf(c3.w, a3.w, t0); t1 = fmaf(c3.w, b3.w, t1);
        Tp[mg * PAD_TP + k * 16 + ij0]     = t0;
        Tp[mg * PAD_TP + k * 16 + ij0 + 1] = t1;
    }
}

__device__ __forceinline__ void t_reduce(const float* __restrict__ Tp,
                                         float* __restrict__ T, int tid) {
    if (tid < 160) {
        float t = 0.f;
        #pragma unroll
        for (int mg = 0; mg < 16; ++mg) t += Tp[mg * PAD_TP + tid];
        T[tid] = t;
    }
}

// s_part[k][i][le] = sum_j T[k][i*4+j] * w[k][j*4+le]
__device__ __forceinline__ void s_write(const float* __restrict__ T,
                                        const float* __restrict__ w,
                                        float* __restrict__ s_base, int tid) {
    if (tid < 160) {
        const int k = tid >> 4;
        const int i = (tid >> 2) & 3;
        const int le = tid & 3;
        const float4 t4 = *(const float4*)(T + k * 16 + i * 4);
        float sv = 0.f;
        sv = fmaf(t4.x, w[k * 16 + 0 * 4 + le], sv);
        sv = fmaf(t4.y, w[k * 16 + 1 * 4 + le], sv);
        sv = fmaf(t4.z, w[k * 16 + 2 * 4 + le], sv);
        sv = fmaf(t4.w, w[k * 16 + 3 * 4 + le], sv);
        s_base[tid] = sv;
    }
}

__global__ __launch_bounds__(256) void caps_main(
    const float* __restrict__ l, const float* __restrict__ g,
    const float* __restrict__ weight,
    const float* __restrict__ sp0, const float* __restrict__ sp1,
    float* __restrict__ s_out, int nv)
{
    __shared__ __align__(16) float w_lds[160];
    __shared__ __align__(16) float E_lds[160];
    __shared__ __align__(16) float lrT[16 * PAD_LRT];
    __shared__ __align__(16) float c_lds[KC * 256];
    __shared__ __align__(16) float Tp[16 * PAD_TP];
    __shared__ __align__(16) float T_lds[160];

    const int tid = threadIdx.x;
    const int n = blockIdx.x >> 5;
    const int c = blockIdx.x & 31;

    if (tid < 160) w_lds[tid] = weight[c * 160 + tid];

    // per-thread pose (coalesced 256B/wave-inst) + transposed LDS copy
    float lr[16];
    const float* lbase = l + (size_t)(n * CB + c) * 4096 + tid;
    #pragma unroll
    for (int ij = 0; ij < 16; ++ij) lr[ij] = lbase[ij * 256];
    #pragma unroll
    for (int ij = 0; ij < 16; ++ij) lrT[ij * PAD_LRT + tid] = lr[ij];
    __syncthreads();                                    // S0: w_lds, lrT ready

    // aeff in-register; E via 4-lane-cluster shuffles (no LDS, no extra sync).
    // Thread tid = k*16+i*4+j needs aeff[k*16+i*4+l], held by lanes (tid&60)|l
    // of the SAME wave (4-groups never straddle waves).
    float a_self = 0.f;
    if (tid < 160) {
        a_self = g[n * 160 + tid];
        if (nv > 0) a_self += squash_term(sp0, n, tid);
        if (nv > 1) a_self += squash_term(sp1, n, tid);
    }
    if (tid < 160) {
        const int j = tid & 3;
        const int kbase = tid & ~15;             // k*16
        float e = 0.f;
        #pragma unroll
        for (int l2 = 0; l2 < 4; ++l2) {
            const float av = __shfl(a_self, (tid & 60) + l2, 64);
            e = fmaf(av, w_lds[kbase + j * 4 + l2], e);
        }
        E_lds[tid] = e;
    }
    __syncthreads();                                    // S1: E ready

    softmax_c(lr, E_lds, c_lds, tid);
    __syncthreads();                                    // S2: c ready
    tp_stage(lrT, c_lds, Tp, tid);
    __syncthreads();                                    // S3: Tp ready
    t_reduce(Tp, T_lds, tid);
    __syncthreads();                                    // S4: T ready
    s_write(T_lds, w_lds, s_out + (size_t)blockIdx.x * 160, tid);
}

// final: v = squash(sum_c s2), a = sigmoid(||v||); out = [a(320) | v(5120)]
__global__ __launch_bounds__(256) void caps_final(
    const float* __restrict__ sp2, float* __restrict__ out)
{
    const int idx = blockIdx.x * 256 + threadIdx.x;  // 0..5119
    const int nk = idx >> 4;
    const int d = idx & 15;
    const int n = nk / 10;
    const int k = nk - n * 10;
    const float* sp = sp2 + (size_t)n * (CB * 160) + k * 16 + d;
    float t0 = 0.f, t1 = 0.f, t2 = 0.f, t3 = 0.f;
    #pragma unroll
    for (int cc = 0; cc < 32; cc += 4) {
        t0 += sp[cc * 160];       t1 += sp[(cc + 1) * 160];
        t2 += sp[(cc + 2) * 160]; t3 += sp[(cc + 3) * 160];
    }
    float ssum = (t0 + t1) + (t2 + t3);
    float sq = ssum * ssum;
    sq += __shfl_xor(sq, 1, 16);
    sq += __shfl_xor(sq, 2, 16);
    sq += __shfl_xor(sq, 4, 16);
    sq += __shfl_xor(sq, 8, 16);
    sq = fmaxf(sq, 1e-30f);
    out[320 + nk * 16 + d] = ssum * sq / ((1.f + sq) * sqrtf(sq));
    if (d == 0) {
        const float nrm = sq / (1.f + sq);   // == ||v||
        out[nk] = 1.f / (1.f + __expf(-nrm));
    }
}

extern "C" void kernel_launch(void* const* d_in, const int* in_sizes, int n_in,
                              void* d_out, int out_size, void* d_ws, size_t ws_size,
                              hipStream_t stream) {
    const float* l = (const float*)d_in[0];
    const float* g = (const float*)d_in[1];
    const float* w = (const float*)d_in[2];
    float* out = (float*)d_out;
    float* ws = (float*)d_ws;

    float* s0 = ws;                 // (N,C,160) = 163840 floats each
    float* s1 = ws + 163840;
    float* s2 = ws + 327680;

    caps_main<<<dim3(NB * CB), dim3(256), 0, stream>>>(l, g, w, nullptr, nullptr, s0, 0);
    caps_main<<<dim3(NB * CB), dim3(256), 0, stream>>>(l, g, w, s0, nullptr, s1, 1);
    caps_main<<<dim3(NB * CB), dim3(256), 0, stream>>>(l, g, w, s0, s1, s2, 2);
    caps_final<<<dim3(20), dim3(256), 0, stream>>>(s2, out);
}